// Round 10
// baseline (288.436 us; speedup 1.0000x reference)
//
#include <hip/hip_runtime.h>
#include <hip/hip_bf16.h>
#include <type_traits>

typedef __bf16 bf16;
typedef __bf16 bf16x2 __attribute__((ext_vector_type(2)));
typedef __bf16 bf16x4 __attribute__((ext_vector_type(4)));
typedef __bf16 bf16x8 __attribute__((ext_vector_type(8)));
typedef float f32x4 __attribute__((ext_vector_type(4)));

#define AS1 __attribute__((address_space(1)))
#define AS3 __attribute__((address_space(3)))

// 0.125 (1/sqrt(64)) * log2(e): folded into Q so attn scores are log2-domain.
#define KAPPA 0.180336880111f

__device__ __forceinline__ void load_lds16(const void* g, void* l) {
  __builtin_amdgcn_global_load_lds((AS1 void*)g, (AS3 void*)l, 16, 0, 0);
}
__device__ __forceinline__ float exp2_fast(float x) {
  return __builtin_amdgcn_exp2f(x);
}

// ---------------------------------------------------------------------------
// fp32->bf16 + MFMA-fragment shuffle for BOTH x and the weights.
// Layout: element (n,k) -> byte ((n>>6)*NKB + (k>>5))*4096 [64x32 block,
// NKB=64 kblocks] + ((n>>4)&3)*1024 [frag] + ((n&15)|(((k>>3)&3)<<4))*16
// [lane] + (k&7)*2. A GEMM wave then loads frag i of block (n0,tk) with ONE
// coalesced dwordx4 at blk*4096 + i*1024 + lane*16 -- BOTH operands go
// direct to registers; the GEMM K-loop uses no LDS and no barriers.
// One 256-thr block per 64x32 source block; writes 1KB-contiguous per wave.
// Grid: x 4096 blocks | wqkv 3072 | wob 2048 = 9216.
// ---------------------------------------------------------------------------
__global__ void f2b_all(const float* __restrict__ x, const float* __restrict__ wq,
                        const float* __restrict__ wk, const float* __restrict__ wv,
                        const float* __restrict__ wo, bf16* __restrict__ xb,
                        bf16* __restrict__ wqkv, bf16* __restrict__ wob) {
  int bid = blockIdx.x;
  const float* src;
  bf16* dst;
  int nblk, kblk, nb;
  if (bid < 4096) {  // x: 64 mblks x 64 kblks
    nblk = bid >> 6;
    kblk = bid & 63;
    src = x;
    nb = nblk * 64;
    dst = xb;
  } else if (bid < 7168) {  // wqkv: 48 nblks x 64 kblks
    int b2 = bid - 4096;
    nblk = b2 >> 6;
    kblk = b2 & 63;
    int n0 = nblk * 64;
    if (n0 < 2048) { src = wq; nb = n0; }
    else if (n0 < 2560) { src = wk; nb = n0 - 2048; }
    else { src = wv; nb = n0 - 2560; }
    dst = wqkv;
  } else {  // wob: 32 nblks x 64 kblks
    int b3 = bid - 7168;
    nblk = b3 >> 6;
    kblk = b3 & 63;
    src = wo;
    nb = nblk * 64;
    dst = wob;
  }
  const int t = threadIdx.x, j = t >> 6, l = t & 63;
  const int n = nb + j * 16 + (l & 15);
  const int k = kblk * 32 + (l >> 4) * 8;
  float4 v0 = *(const float4*)(src + (size_t)n * 2048 + k);
  float4 v1 = *(const float4*)(src + (size_t)n * 2048 + k + 4);
  bf16x8 o = {(bf16)v0.x, (bf16)v0.y, (bf16)v0.z, (bf16)v0.w,
              (bf16)v1.x, (bf16)v1.y, (bf16)v1.z, (bf16)v1.w};
  *(bf16x8*)((char*)dst + ((size_t)(nblk * 64 + kblk)) * 4096 + j * 1024 +
             l * 16) = o;
}

// ---------------------------------------------------------------------------
// Fused QKV projection GEMM -- BARRIER-FREE REGISTER FLATMM.
// History: 747 TF plateau at the 128^2 LDS-ring structure; direct experiments
// exonerated scheduling (r2/3/6), LDS BW (r7), cache locality (r8). Last
// suspect: barrier lockstep itself. Here BOTH operands are fragment-shuffled
// in workspace, so each wave loads its 8 fragments/tile (1KB-contiguous
// dwordx4, L2/L1-resident panels) DIRECT to registers, one tile ahead:
// the K-loop has NO LDS, NO s_barrier, NO manual waitcnt -- plain register
// dataflow, which the compiler schedules with exact counted vmcnt natively
// (the m97 drain pathology is global_load_lds+barrier-specific). Waves
// drift freely (m114 overlap, zero sync).
//   128x128 tile, 4 waves, BK=32; grid (24,32)=768 = 3 blocks/CU.
//   VGPR ~140 (64 acc + 64 frag 2-sets + addr) -> 3 waves/SIMD.
//   Reg sets alternate via 2x-unrolled body (static indexing).
// L2/CU/iter ~48KB (same as r9; under the ~56 B/cy/CU L2 ceiling); FETCH
// may drift up -- r8 proved +55% HBM traffic costs zero time here.
// Epilogue (round-0 verified): bn<16 Q+rope*KAPPA; 16-19 K+rope; 20-23 V^T.
// ---------------------------------------------------------------------------
__global__ __launch_bounds__(256, 3) void gemm_qkv(const bf16* __restrict__ A,
                                                   const bf16* __restrict__ Bw,
                                                   const float* __restrict__ fc,
                                                   const float* __restrict__ fs,
                                                   bf16* __restrict__ Qro,
                                                   bf16* __restrict__ Kro,
                                                   bf16* __restrict__ Vt) {
  const int t = threadIdx.x;
  const int wave = t >> 6, lane = t & 63, qd = lane >> 4, ln = lane & 15;
  const int wm = (wave >> 1) * 64;
  const int wn = (wave & 1) * 64;
  const int bn = blockIdx.x;  // 0..23 (Q:0-15, K:16-19, V:20-23)
  const size_t bm = (size_t)blockIdx.y * 128;

  // Fragment bases: A block-row mblk0 (256KB stride), B block-col n0.
  const int mblk0 = (int)(blockIdx.y * 2) + (wm >> 6);
  const char* Aw = (const char*)A + (size_t)mblk0 * 262144 + (size_t)lane * 16;
  const int n0 = bn * 2 + (wn >> 6);
  const char* Bb = (const char*)Bw + (size_t)n0 * 262144 + (size_t)lane * 16;

  f32x4 acc[4][4] = {};
  bf16x8 a0[4], b0[4], a1[4], b1[4];

  auto loadT = [&](int tk, bf16x8 (&a)[4], bf16x8 (&b)[4]) {
#pragma unroll
    for (int i = 0; i < 4; i++)
      a[i] = *(const bf16x8*)(Aw + (size_t)tk * 4096 + i * 1024);
#pragma unroll
    for (int j = 0; j < 4; j++)
      b[j] = *(const bf16x8*)(Bb + (size_t)tk * 4096 + j * 1024);
  };

  loadT(0, a0, b0);
  loadT(1, a1, b1);

  // Per step: MFMA tile tk from its set (compiler emits the counted vmcnt
  // before first use), then refill the just-consumed set with tile tk+2.
  auto step = [&](int tk, bf16x8 (&ca)[4], bf16x8 (&cb)[4]) {
    __builtin_amdgcn_s_setprio(1);
#pragma unroll
    for (int i = 0; i < 4; i++)
#pragma unroll
      for (int j = 0; j < 4; j++)
        acc[i][j] = __builtin_amdgcn_mfma_f32_16x16x32_bf16(ca[i], cb[j],
                                                            acc[i][j], 0, 0, 0);
    __builtin_amdgcn_s_setprio(0);
    if (tk + 2 < 64) loadT(tk + 2, ca, cb);
  };

#pragma unroll 1
  for (int tk = 0; tk < 64; tk += 2) {
    step(tk, a0, b0);
    step(tk + 1, a1, b1);
  }

  // ---- epilogue (round-0 verified) ----
  const int b = (int)(bm >> 11);
  const int sb = (int)(bm & 2047) + wm;
  const bool odd = ln & 1;

  if (bn < 20) {  // Q or K: rope, head-major output
    const bool isQ = bn < 16;
    const float kap = isQ ? KAPPA : 1.0f;
    const int hh = isQ ? (bn * 2 + (wn >> 6)) : ((bn - 16) * 2 + (wn >> 6));
    bf16* dst = isQ ? (Qro + ((size_t)(b * 32 + hh) * 2048) * 64)
                    : (Kro + ((size_t)(b * 8 + hh) * 2048) * 64);
#pragma unroll
    for (int i = 0; i < 4; i++) {
#pragma unroll
      for (int j = 0; j < 4; j++) {
        const int d = j * 16 + ln;
        const int i_f = d >> 1;
#pragma unroll
        for (int r = 0; r < 4; r++) {
          int s = sb + i * 16 + qd * 4 + r;
          float v = acc[i][j][r];
          float p = __shfl_xor(v, 1);
          float cv = fc[s * 32 + i_f] * kap;
          float sv = fs[s * 32 + i_f] * kap;
          float o = odd ? (p * sv + v * cv) : (v * cv - p * sv);
          dst[(size_t)s * 64 + d] = (bf16)o;
        }
      }
    }
  } else {  // V: write transposed (B,8,64,S)
    const int kh = (bn - 20) * 2 + (wn >> 6);
#pragma unroll
    for (int i = 0; i < 4; i++)
#pragma unroll
      for (int j = 0; j < 4; j++) {
        const int d = j * 16 + ln;
        int s = sb + i * 16 + qd * 4;
        bf16x4 ov = {(bf16)acc[i][j][0], (bf16)acc[i][j][1],
                     (bf16)acc[i][j][2], (bf16)acc[i][j][3]};
        *(bf16x4*)&Vt[((size_t)(b * 8 + kh) * 64 + d) * 2048 + s] = ov;
      }
  }
}

// ---------------------------------------------------------------------------
// Output projection GEMM (r9 form, unchanged): 64x128 tile, 4 blocks/CU,
// A via 3-slot LDS ring, B direct-to-registers from shuffled wob,
// counted vmcnt.
// ---------------------------------------------------------------------------
__global__ __launch_bounds__(256, 4) void gemm_bt(const bf16* __restrict__ A,
                                                  const bf16* __restrict__ Bw,
                                                  float* __restrict__ C) {
  const int K = 2048, N = 2048;
  __shared__ bf16 As[3][64][32];  // 12 KB ring
  const int t = threadIdx.x;
  const int wave = t >> 6, lane = t & 63, qd = lane >> 4, ln = lane & 15;
  const int wm = (wave >> 1) * 32;
  const int wn = (wave & 1) * 64;
  const size_t bm = (size_t)blockIdx.y * 64;
  const size_t bn = (size_t)blockIdx.x * 128;

  const bf16* Ab = A + bm * (size_t)K;
  const int n0 = (int)(bn >> 6) + (wn >> 6);
  const char* Bb = (const char*)Bw + (size_t)n0 * 262144 + (size_t)lane * 16;

  auto stage = [&](int tk, int slot) {
    int ro = t >> 2, gs = (t & 3) ^ ((ro >> 1) & 3);
    load_lds16(Ab + (size_t)ro * K + tk * 32 + gs * 8,
               (char*)As + slot * 4096 + wave * 1024);
  };

  f32x4 acc[2][4] = {};
  const int segoff = (qd ^ ((ln >> 1) & 3)) << 4;
  bf16x8 b0[4], b1[4];

  // Prologue: B(0):4, stage(0):1, stage(1):1 -> need B0+stage0: vmcnt(1).
#pragma unroll
  for (int j = 0; j < 4; j++)
    b0[j] = *(const bf16x8*)(Bb + (size_t)j * 1024);
  stage(0, 0);
  stage(1, 1);
  asm volatile("s_waitcnt vmcnt(1)" ::: "memory");
  __builtin_amdgcn_s_barrier();

  auto step = [&](int tk, bf16x8 (&cb)[4], bf16x8 (&nb)[4]) {
    if (tk < 62) stage(tk + 2, (tk + 2) % 3);
    if (tk < 63) {
#pragma unroll
      for (int j = 0; j < 4; j++)
        nb[j] = *(const bf16x8*)(Bb + (size_t)(tk + 1) * 4096 + j * 1024);
    }
    const char* Asl = (const char*)As + (tk % 3) * 4096;
    bf16x8 af[2];
#pragma unroll
    for (int i = 0; i < 2; i++)
      af[i] = *(const bf16x8*)(Asl + (wm + i * 16 + ln) * 64 + segoff);
    if (tk <= 61) asm volatile("s_waitcnt lgkmcnt(0) vmcnt(5)" ::: "memory");
    else if (tk == 62) asm volatile("s_waitcnt lgkmcnt(0) vmcnt(4)" ::: "memory");
    else asm volatile("s_waitcnt lgkmcnt(0) vmcnt(0)" ::: "memory");
    __builtin_amdgcn_sched_barrier(0);
    __builtin_amdgcn_s_setprio(1);
#pragma unroll
    for (int i = 0; i < 2; i++)
#pragma unroll
      for (int j = 0; j < 4; j++)
        acc[i][j] = __builtin_amdgcn_mfma_f32_16x16x32_bf16(af[i], cb[j],
                                                            acc[i][j], 0, 0, 0);
    __builtin_amdgcn_s_setprio(0);
    if (tk < 63) __builtin_amdgcn_s_barrier();
  };

  for (int tk = 0; tk < 64; tk += 2) {
    step(tk, b0, b1);
    step(tk + 1, b1, b0);
  }

#pragma unroll
  for (int i = 0; i < 2; i++)
#pragma unroll
    for (int j = 0; j < 4; j++)
#pragma unroll
      for (int r = 0; r < 4; r++) {
        size_t row = bm + wm + i * 16 + qd * 4 + r;
        size_t col = bn + wn + j * 16 + ln;
        C[row * N + col] = acc[i][j][r];
      }
}

// ---------------------------------------------------------------------------
// Flash attention (r5 form, verified). S^T formulation, causal, log2-domain
// fixed-point softmax p = 2^(s-16). Q fragments in registers; K/V 2-slot
// ring staged at top of iteration; one __syncthreads per tile.
// Q:(B,32,S,64)  K:(B,8,S,64)  Vt:(B,8,64,S)  ->  O:(B,S,32,64)
// ---------------------------------------------------------------------------
__global__ __launch_bounds__(256, 3) void attn_fwd(const bf16* __restrict__ Q,
                                                   const bf16* __restrict__ Kg,
                                                   const bf16* __restrict__ Vg,
                                                   bf16* __restrict__ O) {
  __shared__ bf16 Ks[2][64][64];  // 16 KB ring
  __shared__ bf16 Vs[2][64][64];  // 16 KB ring, [d][k]
  __shared__ bf16 Ps[128][64];    // [q][k], swizzled
  const int t = threadIdx.x;
  const int wave = t >> 6, lane = t & 63, qd = lane >> 4, ln = lane & 15;
  const int bid = blockIdx.x;
  const int qt = 15 - (bid >> 6);  // longest blocks dispatch first
  const int bh = bid & 63;
  const int b = bh >> 5, h = bh & 31, kh = h >> 2;
  const bf16* Qb = Q + ((size_t)(b * 32 + h) * 2048 + qt * 128) * 64;  // contiguous
  const bf16* Kb = Kg + (size_t)(b * 8 + kh) * 2048 * 64;              // contiguous
  const bf16* Vb = Vg + (size_t)(b * 8 + kh) * 64 * 2048;              // row stride 2048
  char* PsB = (char*)Ps;

  bf16x8 qf[2][2];
#pragma unroll
  for (int kk = 0; kk < 2; kk++)
#pragma unroll
    for (int mi = 0; mi < 2; mi++)
      qf[kk][mi] = *(const bf16x8*)(Qb + (wave * 32 + mi * 16 + ln) * 64 +
                                    (kk * 4 + qd) * 8);

  auto stageKV = [&](int kb, int buf) {
#pragma unroll
    for (int i = 0; i < 2; i++) {
      int e = i * 256 + t;
      int row = e >> 3, sg = (e & 7) ^ (row & 7);
      load_lds16(Kb + (size_t)(kb * 64 + row) * 64 + sg * 8,
                 (char*)Ks + buf * 8192 + i * 4096 + wave * 1024);
      load_lds16(Vb + (size_t)row * 2048 + kb * 64 + sg * 8,
                 (char*)Vs + buf * 8192 + i * 4096 + wave * 1024);
    }
  };

  f32x4 o_acc[4][2] = {};
  float l_st[2] = {0.f, 0.f};
  const int q0 = qt * 128 + wave * 32;
  const int nkb = 2 * qt + 2;

  stageKV(0, 0);
  __syncthreads();  // K0/V0 landed (vmcnt drain)

  for (int kb = 0; kb < nkb; kb++) {
    const int cur = kb & 1;
    if (kb + 1 < nkb) stageKV(kb + 1, cur ^ 1);
    const char* Ksl = (const char*)Ks + cur * 8192;
    const char* Vsl = (const char*)Vs + cur * 8192;

    // S^T = K*Q^T
    f32x4 s_acc[4][2] = {};
#pragma unroll
    for (int kk = 0; kk < 2; kk++) {
      bf16x8 ak[4];
#pragma unroll
      for (int j = 0; j < 4; j++) {
        int row = j * 16 + ln;
        int ph = (kk * 4 + qd) ^ (ln & 7);
        ak[j] = *(const bf16x8*)(Ksl + row * 128 + ph * 16);
      }
#pragma unroll
      for (int j = 0; j < 4; j++)
#pragma unroll
        for (int mi = 0; mi < 2; mi++)
          s_acc[j][mi] = __builtin_amdgcn_mfma_f32_16x16x32_bf16(
              ak[j], qf[kk][mi], s_acc[j][mi], 0, 0, 0);
    }

    // fixed-point softmax: p = 2^(s-16); masked -> exact 0
    auto smax = [&](auto maskc) {
      constexpr bool MASK = decltype(maskc)::value;
#pragma unroll
      for (int mi = 0; mi < 2; mi++) {
        const int qv = q0 + mi * 16 + ln;
        const int prow = wave * 32 + mi * 16 + ln;
        float rs = 0.f;
#pragma unroll
        for (int j = 0; j < 4; j++) {
          bf16x4 pk;
#pragma unroll
          for (int r = 0; r < 4; r++) {
            float s = s_acc[j][mi][r];
            if (MASK) {
              int k_glob = kb * 64 + j * 16 + qd * 4 + r;
              if (k_glob > qv) s = -1e5f;
            }
            float pv = exp2_fast(s - 16.f);
            rs += pv;
            pk[r] = (bf16)pv;
          }
          int ps = (j * 2 + (qd >> 1)) ^ (ln & 7);
          *(bf16x4*)(PsB + prow * 128 + ps * 16 + (qd & 1) * 8) = pk;
        }
        l_st[mi] += rs;
      }
    };
    if (kb * 64 + 63 > q0) smax(std::true_type{});
    else smax(std::false_type{});

    // O^T += V^T * P^T  (Ps wave-private; lgkmcnt orders write->read)
#pragma unroll
    for (int kk = 0; kk < 2; kk++) {
      bf16x8 av[4], bp[2];
#pragma unroll
      for (int dj = 0; dj < 4; dj++) {
        int row = dj * 16 + ln;
        int ph = (kk * 4 + qd) ^ (ln & 7);
        av[dj] = *(const bf16x8*)(Vsl + row * 128 + ph * 16);
      }
#pragma unroll
      for (int mi = 0; mi < 2; mi++) {
        int prow = wave * 32 + mi * 16 + ln;
        int ph = (kk * 4 + qd) ^ (ln & 7);
        bp[mi] = *(const bf16x8*)(PsB + prow * 128 + ph * 16);
      }
#pragma unroll
      for (int dj = 0; dj < 4; dj++)
#pragma unroll
        for (int mi = 0; mi < 2; mi++)
          o_acc[dj][mi] = __builtin_amdgcn_mfma_f32_16x16x32_bf16(
              av[dj], bp[mi], o_acc[dj][mi], 0, 0, 0);
    }

    __syncthreads();
  }

  // epilogue: reduce l across quads (each quad summed a disjoint k-subset)
#pragma unroll
  for (int mi = 0; mi < 2; mi++) {
    float lt = l_st[mi];
    lt += __shfl_xor(lt, 16);
    lt += __shfl_xor(lt, 32);
    float inv = 1.f / lt;
    int q_idx = qt * 128 + wave * 32 + mi * 16 + ln;
#pragma unroll
    for (int dj = 0; dj < 4; dj++) {
      bf16x4 ov;
#pragma unroll
      for (int r = 0; r < 4; r++) ov[r] = (bf16)(o_acc[dj][mi][r] * inv);
      *(bf16x4*)&O[((size_t)(b * 2048 + q_idx) * 32 + h) * 64 + dj * 16 + qd * 4] = ov;
    }
  }
}

// ---------------------------------------------------------------------------
extern "C" void kernel_launch(void* const* d_in, const int* in_sizes, int n_in,
                              void* d_out, int out_size, void* d_ws,
                              size_t ws_size, hipStream_t stream) {
  const float* x = (const float*)d_in[0];
  const float* fc = (const float*)d_in[1];
  const float* fs = (const float*)d_in[2];
  const float* wq = (const float*)d_in[3];
  const float* wk = (const float*)d_in[4];
  const float* wv = (const float*)d_in[5];
  const float* wo = (const float*)d_in[6];
  float* out = (float*)d_out;

  char* ws = (char*)d_ws;
  const size_t MB = (size_t)1 << 20;
  bf16* xb   = (bf16*)(ws + 0 * MB);   // 16 MB (4096,2048) fragment-shuffled
  bf16* wqkv = (bf16*)(ws + 16 * MB);  // 12 MB fragment-shuffled
  bf16* wob  = (bf16*)(ws + 28 * MB);  // 8 MB fragment-shuffled
  bf16* Qro  = (bf16*)(ws + 36 * MB);  // 16 MB (B,32,S,64), roped*KAPPA
  bf16* Kro  = (bf16*)(ws + 52 * MB);  // 4 MB  (B,8,S,64), roped
  bf16* Vt   = (bf16*)(ws + 56 * MB);  // 4 MB  (B,8,64,S)
  bf16* Oa   = (bf16*)(ws + 60 * MB);  // 16 MB (B,S,32,64)

  dim3 blk(256);
  f2b_all<<<9216, blk, 0, stream>>>(x, wq, wk, wv, wo, xb, wqkv, wob);
  gemm_qkv<<<dim3(24, 32), blk, 0, stream>>>(xb, wqkv, fc, fs, Qro, Kro, Vt);
  attn_fwd<<<1024, blk, 0, stream>>>(Qro, Kro, Vt, Oa);
  gemm_bt<<<dim3(16, 64), blk, 0, stream>>>(Oa, wob, out);
}

// Round 11
// 285.261 us; speedup vs baseline: 1.0111x; 1.0111x over previous
//
#include <hip/hip_runtime.h>
#include <hip/hip_bf16.h>
#include <type_traits>

typedef __bf16 bf16;
typedef __bf16 bf16x2 __attribute__((ext_vector_type(2)));
typedef __bf16 bf16x4 __attribute__((ext_vector_type(4)));
typedef __bf16 bf16x8 __attribute__((ext_vector_type(8)));
typedef float f32x4 __attribute__((ext_vector_type(4)));

#define AS1 __attribute__((address_space(1)))
#define AS3 __attribute__((address_space(3)))

// 0.125 (1/sqrt(64)) * log2(e): folded into Q so attn scores are log2-domain.
#define KAPPA 0.180336880111f

__device__ __forceinline__ void load_lds16(const void* g, void* l) {
  __builtin_amdgcn_global_load_lds((AS1 void*)g, (AS3 void*)l, 16, 0, 0);
}
__device__ __forceinline__ float exp2_fast(float x) {
  return __builtin_amdgcn_exp2f(x);
}

// ---------------------------------------------------------------------------
// fp32->bf16 conversions:
//   x  -> FRAGMENT-SHUFFLED xb (qkv reads A direct-to-reg): element (n,k) ->
//         byte ((n>>6)*64+(k>>5))*4096 + ((n>>4)&3)*1024 +
//         ((n&15)|(((k>>3)&3)<<4))*16 + (k&7)*2.
//   wq/wk/wv -> ROW-MAJOR concat wqkv (qkv stages B through LDS, shared by
//         all 4 waves -- zero-duplication design).
//   wo -> FRAGMENT-SHUFFLED wob (bt reads B direct-to-reg).
// Grid: x 4096 shuffle-blocks | wqkv 6144 linear | wob 2048 shuffle = 12288.
// ---------------------------------------------------------------------------
__global__ void f2b_all(const float* __restrict__ x, const float* __restrict__ wq,
                        const float* __restrict__ wk, const float* __restrict__ wv,
                        const float* __restrict__ wo, bf16* __restrict__ xb,
                        bf16* __restrict__ wqkv, bf16* __restrict__ wob) {
  int bid = blockIdx.x;
  if (bid >= 4096 && bid < 10240) {  // wqkv row-major, 4 f32/thread
    int b2 = bid - 4096;
    const float* src;
    bf16* dst = wqkv;
    int off;
    if (b2 < 4096) { src = wq; off = b2; }
    else if (b2 < 5120) { src = wk; dst = wqkv + 4194304; off = b2 - 4096; }
    else { src = wv; dst = wqkv + 5242880; off = b2 - 5120; }
    int i = (off * 256 + threadIdx.x) * 4;
    float4 v = *(const float4*)(src + i);
    bf16x4 o = {(bf16)v.x, (bf16)v.y, (bf16)v.z, (bf16)v.w};
    *(bf16x4*)(dst + i) = o;
    return;
  }
  // shuffle path (x or wo)
  const float* src;
  bf16* dst;
  int nblk, kblk;
  if (bid < 4096) {  // x: 64 mblks x 64 kblks
    nblk = bid >> 6;
    kblk = bid & 63;
    src = x;
    dst = xb;
  } else {  // wo: 32 nblks x 64 kblks
    int b3 = bid - 10240;
    nblk = b3 >> 6;
    kblk = b3 & 63;
    src = wo;
    dst = wob;
  }
  const int t = threadIdx.x, j = t >> 6, l = t & 63;
  const int n = nblk * 64 + j * 16 + (l & 15);
  const int k = kblk * 32 + (l >> 4) * 8;
  float4 v0 = *(const float4*)(src + (size_t)n * 2048 + k);
  float4 v1 = *(const float4*)(src + (size_t)n * 2048 + k + 4);
  bf16x8 o = {(bf16)v0.x, (bf16)v0.y, (bf16)v0.z, (bf16)v0.w,
              (bf16)v1.x, (bf16)v1.y, (bf16)v1.z, (bf16)v1.w};
  *(bf16x8*)((char*)dst + ((size_t)(nblk * 64 + kblk)) * 4096 + j * 1024 +
             l * 16) = o;
}

// ---------------------------------------------------------------------------
// Fused QKV projection GEMM -- ZERO-DUPLICATION HYBRID.
// The 10-round invariant (MfmaUtil ~30% across all schedules) is explained
// quantitatively by L2 BW x operand duplication: ideal 128^2 tile = 63.5
// B/cy/CU at full rate vs ~56 B/cy budget (88% ceiling), but every prior
// variant duplicated A or B x2 per block (waves re-loading shared frags) ->
// 95-127 B/cy -> 44-54% ceiling -> measured 30%. This version fetches each
// operand byte EXACTLY ONCE per block:
//   A: direct-to-registers, WAVE-PRIVATE rows (4 waves x 32-row strips,
//      acc[2][8]); xb fragment-shuffled (r10-verified load path).
//   B: staged once into a 3-slot LDS ring via global_load_lds (r5-verified
//      swizzle + ledger), ds_read by all 4 waves (8 frags each).
// 128x128 tile, 4 waves, BK=32, grid (24,32)=768 = 3 blocks/CU, LDS 24KB.
// vmcnt ledger: iter tk issues [stageB(tk+2):2, loadA(tk+1):2]; outstanding
//   before wait = stageB(tk+1)+A(tk)+stageB(tk+2)+A(tk+1) = 8; vmcnt(4)
//   retires stageB(tk+1) (ds_read next iter) + A(tk) (MFMA now). Tail:
//   tk==62 -> vmcnt(2), tk==63 -> vmcnt(0). lgkm(0) covers B ds_reads.
//   Slot-reuse: stageB(tk+2) overwrites slot (tk-1)%3; its readers passed
//   lgkm(0)+barrier in iter tk-1.
// B swizzle: seg ^= (ro>>1)&3 on global source (VERIFIED conflict-free);
//   read seg offset = per-thread constant (qd^((ln>>1)&3))*16.
// Epilogue (round-0-verified math, re-indexed for 32x128 wave tile):
//   head = j>>2, d = (j&3)*16+ln, s = (bm&2047)+wave*32+i*16+qd*4+r.
//   bn<16 Q+rope*KAPPA; 16-19 K+rope; 20-23 V^T.
// ---------------------------------------------------------------------------
__global__ __launch_bounds__(256, 3) void gemm_qkv(const bf16* __restrict__ A,
                                                   const bf16* __restrict__ Bw,
                                                   const float* __restrict__ fc,
                                                   const float* __restrict__ fs,
                                                   bf16* __restrict__ Qro,
                                                   bf16* __restrict__ Kro,
                                                   bf16* __restrict__ Vt) {
  const int K = 2048;
  __shared__ bf16 Bs[3][128][32];  // 24 KB ring
  const int t = threadIdx.x;
  const int wave = t >> 6, lane = t & 63, qd = lane >> 4, ln = lane & 15;
  const int bn = blockIdx.x;  // 0..23 (Q:0-15, K:16-19, V:20-23)
  const size_t bm = (size_t)blockIdx.y * 128;

  // A: wave-private 32-row strip, direct from fragment-shuffled xb.
  const int mblk = (int)(blockIdx.y * 2) + (wave >> 1);
  const int j0 = (wave & 1) * 2;
  const char* Aw = (const char*)A + (size_t)mblk * 262144 +
                   (size_t)j0 * 1024 + (size_t)lane * 16;
  // B: row-major wqkv panel for this 128-col block.
  const bf16* Bb = Bw + (size_t)bn * 128 * K;

  auto stageB = [&](int tk, int slot) {
#pragma unroll
    for (int sub = 0; sub < 2; sub++) {
      int e = sub * 256 + t;
      int ro = e >> 2, gs = (e & 3) ^ ((ro >> 1) & 3);
      load_lds16(Bb + (size_t)ro * K + tk * 32 + gs * 8,
                 (char*)Bs + slot * 8192 + sub * 4096 + wave * 1024);
    }
  };

  f32x4 acc[2][8] = {};
  const int segoff = (qd ^ ((ln >> 1) & 3)) << 4;
  bf16x8 a0[2], a1[2];

  // Prologue: stage B(0),B(1); load A(0); land everything once.
  stageB(0, 0);
  stageB(1, 1);
#pragma unroll
  for (int i = 0; i < 2; i++)
    a0[i] = *(const bf16x8*)(Aw + (size_t)i * 1024);
  asm volatile("s_waitcnt vmcnt(0)" ::: "memory");
  __builtin_amdgcn_s_barrier();

  // Iter tk: stage B(tk+2), load A(tk+1)->na, ds_read B(tk), wait, 16 MFMA.
  auto step = [&](int tk, bf16x8 (&ca)[2], bf16x8 (&na)[2]) {
    if (tk < 62) stageB(tk + 2, (tk + 2) % 3);
    if (tk < 63) {
#pragma unroll
      for (int i = 0; i < 2; i++)
        na[i] = *(const bf16x8*)(Aw + (size_t)(tk + 1) * 4096 + i * 1024);
    }
    const char* Bsl = (const char*)Bs + (tk % 3) * 8192;
    bf16x8 bf[8];
#pragma unroll
    for (int j = 0; j < 8; j++)
      bf[j] = *(const bf16x8*)(Bsl + (j * 16 + ln) * 64 + segoff);
    if (tk <= 61) asm volatile("s_waitcnt lgkmcnt(0) vmcnt(4)" ::: "memory");
    else if (tk == 62) asm volatile("s_waitcnt lgkmcnt(0) vmcnt(2)" ::: "memory");
    else asm volatile("s_waitcnt lgkmcnt(0) vmcnt(0)" ::: "memory");
    __builtin_amdgcn_sched_barrier(0);
    __builtin_amdgcn_s_setprio(1);
#pragma unroll
    for (int i = 0; i < 2; i++)
#pragma unroll
      for (int j = 0; j < 8; j++)
        acc[i][j] = __builtin_amdgcn_mfma_f32_16x16x32_bf16(ca[i], bf[j],
                                                            acc[i][j], 0, 0, 0);
    __builtin_amdgcn_s_setprio(0);
    if (tk < 63) __builtin_amdgcn_s_barrier();
  };

  for (int tk = 0; tk < 64; tk += 2) {
    step(tk, a0, a1);
    step(tk + 1, a1, a0);
  }

  // ---- epilogue (round-0 math, 32x128 wave tile) ----
  const int b = (int)(bm >> 11);
  const int sb = (int)(bm & 2047) + wave * 32;
  const bool odd = ln & 1;

  if (bn < 20) {  // Q or K: rope, head-major output
    const bool isQ = bn < 16;
    const float kap = isQ ? KAPPA : 1.0f;
    const int hbase = isQ ? bn * 2 : (bn - 16) * 2;
#pragma unroll
    for (int j = 0; j < 8; j++) {
      const int hh = hbase + (j >> 2);
      bf16* dst = isQ ? (Qro + ((size_t)(b * 32 + hh) * 2048) * 64)
                      : (Kro + ((size_t)(b * 8 + hh) * 2048) * 64);
      const int d = (j & 3) * 16 + ln;
      const int i_f = d >> 1;
#pragma unroll
      for (int i = 0; i < 2; i++) {
#pragma unroll
        for (int r = 0; r < 4; r++) {
          int s = sb + i * 16 + qd * 4 + r;
          float v = acc[i][j][r];
          float p = __shfl_xor(v, 1);
          float cv = fc[s * 32 + i_f] * kap;
          float sv = fs[s * 32 + i_f] * kap;
          float o = odd ? (p * sv + v * cv) : (v * cv - p * sv);
          dst[(size_t)s * 64 + d] = (bf16)o;
        }
      }
    }
  } else {  // V: write transposed (B,8,64,S)
#pragma unroll
    for (int j = 0; j < 8; j++) {
      const int kh = (bn - 20) * 2 + (j >> 2);
      const int d = (j & 3) * 16 + ln;
#pragma unroll
      for (int i = 0; i < 2; i++) {
        int s = sb + i * 16 + qd * 4;
        bf16x4 ov = {(bf16)acc[i][j][0], (bf16)acc[i][j][1],
                     (bf16)acc[i][j][2], (bf16)acc[i][j][3]};
        *(bf16x4*)&Vt[((size_t)(b * 8 + kh) * 64 + d) * 2048 + s] = ov;
      }
    }
  }
}

// ---------------------------------------------------------------------------
// Output projection GEMM (r10 form, unchanged): 64x128 tile, 4 blocks/CU,
// A via 3-slot LDS ring, B direct-to-registers from shuffled wob,
// counted vmcnt.
// ---------------------------------------------------------------------------
__global__ __launch_bounds__(256, 4) void gemm_bt(const bf16* __restrict__ A,
                                                  const bf16* __restrict__ Bw,
                                                  float* __restrict__ C) {
  const int K = 2048, N = 2048;
  __shared__ bf16 As[3][64][32];  // 12 KB ring
  const int t = threadIdx.x;
  const int wave = t >> 6, lane = t & 63, qd = lane >> 4, ln = lane & 15;
  const int wm = (wave >> 1) * 32;
  const int wn = (wave & 1) * 64;
  const size_t bm = (size_t)blockIdx.y * 64;
  const size_t bn = (size_t)blockIdx.x * 128;

  const bf16* Ab = A + bm * (size_t)K;
  const int n0 = (int)(bn >> 6) + (wn >> 6);
  const char* Bb = (const char*)Bw + (size_t)n0 * 262144 + (size_t)lane * 16;

  auto stage = [&](int tk, int slot) {
    int ro = t >> 2, gs = (t & 3) ^ ((ro >> 1) & 3);
    load_lds16(Ab + (size_t)ro * K + tk * 32 + gs * 8,
               (char*)As + slot * 4096 + wave * 1024);
  };

  f32x4 acc[2][4] = {};
  const int segoff = (qd ^ ((ln >> 1) & 3)) << 4;
  bf16x8 b0[4], b1[4];

  // Prologue: B(0):4, stage(0):1, stage(1):1 -> need B0+stage0: vmcnt(1).
#pragma unroll
  for (int j = 0; j < 4; j++)
    b0[j] = *(const bf16x8*)(Bb + (size_t)j * 1024);
  stage(0, 0);
  stage(1, 1);
  asm volatile("s_waitcnt vmcnt(1)" ::: "memory");
  __builtin_amdgcn_s_barrier();

  auto step = [&](int tk, bf16x8 (&cb)[4], bf16x8 (&nb)[4]) {
    if (tk < 62) stage(tk + 2, (tk + 2) % 3);
    if (tk < 63) {
#pragma unroll
      for (int j = 0; j < 4; j++)
        nb[j] = *(const bf16x8*)(Bb + (size_t)(tk + 1) * 4096 + j * 1024);
    }
    const char* Asl = (const char*)As + (tk % 3) * 4096;
    bf16x8 af[2];
#pragma unroll
    for (int i = 0; i < 2; i++)
      af[i] = *(const bf16x8*)(Asl + (wm + i * 16 + ln) * 64 + segoff);
    if (tk <= 61) asm volatile("s_waitcnt lgkmcnt(0) vmcnt(5)" ::: "memory");
    else if (tk == 62) asm volatile("s_waitcnt lgkmcnt(0) vmcnt(4)" ::: "memory");
    else asm volatile("s_waitcnt lgkmcnt(0) vmcnt(0)" ::: "memory");
    __builtin_amdgcn_sched_barrier(0);
    __builtin_amdgcn_s_setprio(1);
#pragma unroll
    for (int i = 0; i < 2; i++)
#pragma unroll
      for (int j = 0; j < 4; j++)
        acc[i][j] = __builtin_amdgcn_mfma_f32_16x16x32_bf16(af[i], cb[j],
                                                            acc[i][j], 0, 0, 0);
    __builtin_amdgcn_s_setprio(0);
    if (tk < 63) __builtin_amdgcn_s_barrier();
  };

  for (int tk = 0; tk < 64; tk += 2) {
    step(tk, b0, b1);
    step(tk + 1, b1, b0);
  }

#pragma unroll
  for (int i = 0; i < 2; i++)
#pragma unroll
    for (int j = 0; j < 4; j++)
#pragma unroll
      for (int r = 0; r < 4; r++) {
        size_t row = bm + wm + i * 16 + qd * 4 + r;
        size_t col = bn + wn + j * 16 + ln;
        C[row * N + col] = acc[i][j][r];
      }
}

// ---------------------------------------------------------------------------
// Flash attention (r5/r10 form, verified). S^T formulation, causal,
// log2-domain fixed-point softmax p = 2^(s-16). Q fragments in registers;
// K/V 2-slot ring staged at top of iteration; one __syncthreads per tile.
// Q:(B,32,S,64)  K:(B,8,S,64)  Vt:(B,8,64,S)  ->  O:(B,S,32,64)
// ---------------------------------------------------------------------------
__global__ __launch_bounds__(256, 3) void attn_fwd(const bf16* __restrict__ Q,
                                                   const bf16* __restrict__ Kg,
                                                   const bf16* __restrict__ Vg,
                                                   bf16* __restrict__ O) {
  __shared__ bf16 Ks[2][64][64];  // 16 KB ring
  __shared__ bf16 Vs[2][64][64];  // 16 KB ring, [d][k]
  __shared__ bf16 Ps[128][64];    // [q][k], swizzled
  const int t = threadIdx.x;
  const int wave = t >> 6, lane = t & 63, qd = lane >> 4, ln = lane & 15;
  const int bid = blockIdx.x;
  const int qt = 15 - (bid >> 6);  // longest blocks dispatch first
  const int bh = bid & 63;
  const int b = bh >> 5, h = bh & 31, kh = h >> 2;
  const bf16* Qb = Q + ((size_t)(b * 32 + h) * 2048 + qt * 128) * 64;  // contiguous
  const bf16* Kb = Kg + (size_t)(b * 8 + kh) * 2048 * 64;              // contiguous
  const bf16* Vb = Vg + (size_t)(b * 8 + kh) * 64 * 2048;              // row stride 2048
  char* PsB = (char*)Ps;

  bf16x8 qf[2][2];
#pragma unroll
  for (int kk = 0; kk < 2; kk++)
#pragma unroll
    for (int mi = 0; mi < 2; mi++)
      qf[kk][mi] = *(const bf16x8*)(Qb + (wave * 32 + mi * 16 + ln) * 64 +
                                    (kk * 4 + qd) * 8);

  auto stageKV = [&](int kb, int buf) {
#pragma unroll
    for (int i = 0; i < 2; i++) {
      int e = i * 256 + t;
      int row = e >> 3, sg = (e & 7) ^ (row & 7);
      load_lds16(Kb + (size_t)(kb * 64 + row) * 64 + sg * 8,
                 (char*)Ks + buf * 8192 + i * 4096 + wave * 1024);
      load_lds16(Vb + (size_t)row * 2048 + kb * 64 + sg * 8,
                 (char*)Vs + buf * 8192 + i * 4096 + wave * 1024);
    }
  };

  f32x4 o_acc[4][2] = {};
  float l_st[2] = {0.f, 0.f};
  const int q0 = qt * 128 + wave * 32;
  const int nkb = 2 * qt + 2;

  stageKV(0, 0);
  __syncthreads();  // K0/V0 landed (vmcnt drain)

  for (int kb = 0; kb < nkb; kb++) {
    const int cur = kb & 1;
    if (kb + 1 < nkb) stageKV(kb + 1, cur ^ 1);
    const char* Ksl = (const char*)Ks + cur * 8192;
    const char* Vsl = (const char*)Vs + cur * 8192;

    // S^T = K*Q^T
    f32x4 s_acc[4][2] = {};
#pragma unroll
    for (int kk = 0; kk < 2; kk++) {
      bf16x8 ak[4];
#pragma unroll
      for (int j = 0; j < 4; j++) {
        int row = j * 16 + ln;
        int ph = (kk * 4 + qd) ^ (ln & 7);
        ak[j] = *(const bf16x8*)(Ksl + row * 128 + ph * 16);
      }
#pragma unroll
      for (int j = 0; j < 4; j++)
#pragma unroll
        for (int mi = 0; mi < 2; mi++)
          s_acc[j][mi] = __builtin_amdgcn_mfma_f32_16x16x32_bf16(
              ak[j], qf[kk][mi], s_acc[j][mi], 0, 0, 0);
    }

    // fixed-point softmax: p = 2^(s-16); masked -> exact 0
    auto smax = [&](auto maskc) {
      constexpr bool MASK = decltype(maskc)::value;
#pragma unroll
      for (int mi = 0; mi < 2; mi++) {
        const int qv = q0 + mi * 16 + ln;
        const int prow = wave * 32 + mi * 16 + ln;
        float rs = 0.f;
#pragma unroll
        for (int j = 0; j < 4; j++) {
          bf16x4 pk;
#pragma unroll
          for (int r = 0; r < 4; r++) {
            float s = s_acc[j][mi][r];
            if (MASK) {
              int k_glob = kb * 64 + j * 16 + qd * 4 + r;
              if (k_glob > qv) s = -1e5f;
            }
            float pv = exp2_fast(s - 16.f);
            rs += pv;
            pk[r] = (bf16)pv;
          }
          int ps = (j * 2 + (qd >> 1)) ^ (ln & 7);
          *(bf16x4*)(PsB + prow * 128 + ps * 16 + (qd & 1) * 8) = pk;
        }
        l_st[mi] += rs;
      }
    };
    if (kb * 64 + 63 > q0) smax(std::true_type{});
    else smax(std::false_type{});

    // O^T += V^T * P^T  (Ps wave-private; lgkmcnt orders write->read)
#pragma unroll
    for (int kk = 0; kk < 2; kk++) {
      bf16x8 av[4], bp[2];
#pragma unroll
      for (int dj = 0; dj < 4; dj++) {
        int row = dj * 16 + ln;
        int ph = (kk * 4 + qd) ^ (ln & 7);
        av[dj] = *(const bf16x8*)(Vsl + row * 128 + ph * 16);
      }
#pragma unroll
      for (int mi = 0; mi < 2; mi++) {
        int prow = wave * 32 + mi * 16 + ln;
        int ph = (kk * 4 + qd) ^ (ln & 7);
        bp[mi] = *(const bf16x8*)(PsB + prow * 128 + ph * 16);
      }
#pragma unroll
      for (int dj = 0; dj < 4; dj++)
#pragma unroll
        for (int mi = 0; mi < 2; mi++)
          o_acc[dj][mi] = __builtin_amdgcn_mfma_f32_16x16x32_bf16(
              av[dj], bp[mi], o_acc[dj][mi], 0, 0, 0);
    }

    __syncthreads();
  }

  // epilogue: reduce l across quads (each quad summed a disjoint k-subset)
#pragma unroll
  for (int mi = 0; mi < 2; mi++) {
    float lt = l_st[mi];
    lt += __shfl_xor(lt, 16);
    lt += __shfl_xor(lt, 32);
    float inv = 1.f / lt;
    int q_idx = qt * 128 + wave * 32 + mi * 16 + ln;
#pragma unroll
    for (int dj = 0; dj < 4; dj++) {
      bf16x4 ov;
#pragma unroll
      for (int r = 0; r < 4; r++) ov[r] = (bf16)(o_acc[dj][mi][r] * inv);
      *(bf16x4*)&O[((size_t)(b * 2048 + q_idx) * 32 + h) * 64 + dj * 16 + qd * 4] = ov;
    }
  }
}

// ---------------------------------------------------------------------------
extern "C" void kernel_launch(void* const* d_in, const int* in_sizes, int n_in,
                              void* d_out, int out_size, void* d_ws,
                              size_t ws_size, hipStream_t stream) {
  const float* x = (const float*)d_in[0];
  const float* fc = (const float*)d_in[1];
  const float* fs = (const float*)d_in[2];
  const float* wq = (const float*)d_in[3];
  const float* wk = (const float*)d_in[4];
  const float* wv = (const float*)d_in[5];
  const float* wo = (const float*)d_in[6];
  float* out = (float*)d_out;

  char* ws = (char*)d_ws;
  const size_t MB = (size_t)1 << 20;
  bf16* xb   = (bf16*)(ws + 0 * MB);   // 16 MB (4096,2048) fragment-shuffled
  bf16* wqkv = (bf16*)(ws + 16 * MB);  // 12 MB row-major concat
  bf16* wob  = (bf16*)(ws + 28 * MB);  // 8 MB fragment-shuffled
  bf16* Qro  = (bf16*)(ws + 36 * MB);  // 16 MB (B,32,S,64), roped*KAPPA
  bf16* Kro  = (bf16*)(ws + 52 * MB);  // 4 MB  (B,8,S,64), roped
  bf16* Vt   = (bf16*)(ws + 56 * MB);  // 4 MB  (B,8,64,S)
  bf16* Oa   = (bf16*)(ws + 60 * MB);  // 16 MB (B,S,32,64)

  dim3 blk(256);
  f2b_all<<<12288, blk, 0, stream>>>(x, wq, wk, wv, wo, xb, wqkv, wob);
  gemm_qkv<<<dim3(24, 32), blk, 0, stream>>>(xb, wqkv, fc, fs, Qro, Kro, Vt);
  attn_fwd<<<1024, blk, 0, stream>>>(Qro, Kro, Vt, Oa);
  gemm_bt<<<dim3(16, 64), blk, 0, stream>>>(Oa, wob, out);
}

// Round 12
// 278.555 us; speedup vs baseline: 1.0355x; 1.0241x over previous
//
#include <hip/hip_runtime.h>
#include <hip/hip_bf16.h>
#include <type_traits>

typedef __bf16 bf16;
typedef __bf16 bf16x2 __attribute__((ext_vector_type(2)));
typedef __bf16 bf16x4 __attribute__((ext_vector_type(4)));
typedef __bf16 bf16x8 __attribute__((ext_vector_type(8)));
typedef float f32x4 __attribute__((ext_vector_type(4)));

#define AS1 __attribute__((address_space(1)))
#define AS3 __attribute__((address_space(3)))

// 0.125 (1/sqrt(64)) * log2(e): folded into Q so attn scores are log2-domain.
#define KAPPA 0.180336880111f

__device__ __forceinline__ void load_lds16(const void* g, void* l) {
  __builtin_amdgcn_global_load_lds((AS1 void*)g, (AS3 void*)l, 16, 0, 0);
}
__device__ __forceinline__ float exp2_fast(float x) {
  return __builtin_amdgcn_exp2f(x);
}

// ---------------------------------------------------------------------------
// fp32->bf16 conversions:
//   x  -> FRAGMENT-SHUFFLED xb; wo -> FRAGMENT-SHUFFLED wob;
//   wq/wk/wv -> ROW-MAJOR concat wqkv.
// Shuffle-path thread mapping FIXED for coalescing this round: old mapping
// (n = ..+(l&15)) had 16 lanes reading 16B each from 8KB-strided rows (~4x
// read amplification on 48MB). New: thread t -> n = blk+(t>>2),
// k = (t&3)*8: reads are 128B-contiguous per row-quad (full coalescing);
// writes land permuted WITHIN one 1KB region per wave (wave coalescer
// merges full lines). Layout byte-identical: jf=(n>>4)&3=t>>6,
// slot=(n&15)|(((k>>3)&3)<<4)=((t>>2)&15)|((t&3)<<4).
// Grid: x 4096 shuffle | wqkv 6144 linear | wob 2048 shuffle = 12288.
// ---------------------------------------------------------------------------
__global__ void f2b_all(const float* __restrict__ x, const float* __restrict__ wq,
                        const float* __restrict__ wk, const float* __restrict__ wv,
                        const float* __restrict__ wo, bf16* __restrict__ xb,
                        bf16* __restrict__ wqkv, bf16* __restrict__ wob) {
  int bid = blockIdx.x;
  if (bid >= 4096 && bid < 10240) {  // wqkv row-major, 4 f32/thread
    int b2 = bid - 4096;
    const float* src;
    bf16* dst = wqkv;
    int off;
    if (b2 < 4096) { src = wq; off = b2; }
    else if (b2 < 5120) { src = wk; dst = wqkv + 4194304; off = b2 - 4096; }
    else { src = wv; dst = wqkv + 5242880; off = b2 - 5120; }
    int i = (off * 256 + threadIdx.x) * 4;
    float4 v = *(const float4*)(src + i);
    bf16x4 o = {(bf16)v.x, (bf16)v.y, (bf16)v.z, (bf16)v.w};
    *(bf16x4*)(dst + i) = o;
    return;
  }
  // shuffle path (x or wo), coalesced-read mapping
  const float* src;
  bf16* dst;
  int nblk, kblk;
  if (bid < 4096) {  // x: 64 mblks x 64 kblks
    nblk = bid >> 6;
    kblk = bid & 63;
    src = x;
    dst = xb;
  } else {  // wo: 32 nblks x 64 kblks
    int b3 = bid - 10240;
    nblk = b3 >> 6;
    kblk = b3 & 63;
    src = wo;
    dst = wob;
  }
  const int t = threadIdx.x;
  const int n = nblk * 64 + (t >> 2);
  const int k = kblk * 32 + (t & 3) * 8;
  float4 v0 = *(const float4*)(src + (size_t)n * 2048 + k);
  float4 v1 = *(const float4*)(src + (size_t)n * 2048 + k + 4);
  bf16x8 o = {(bf16)v0.x, (bf16)v0.y, (bf16)v0.z, (bf16)v0.w,
              (bf16)v1.x, (bf16)v1.y, (bf16)v1.z, (bf16)v1.w};
  *(bf16x8*)((char*)dst + ((size_t)(nblk * 64 + kblk)) * 4096 +
             (t >> 6) * 1024 + ((((t >> 2) & 15)) | ((t & 3) << 4)) * 16) = o;
}

// ---------------------------------------------------------------------------
// Fused QKV projection GEMM -- ZERO-DUPLICATION HYBRID (r11, verified:
// 63 us, MfmaUtil 34%, best measured; parked). Every operand byte fetched
// once per block: A direct-to-reg wave-private (fragment-shuffled xb),
// B staged once to 3-slot LDS ring shared by all 4 waves.
// 128x128 tile, 4 waves, BK=32, grid (24,32)=768 = 3 blocks/CU, LDS 24KB.
// vmcnt ledger: iter tk issues [stageB(tk+2):2, loadA(tk+1):2]; vmcnt(4)
//   retires stageB(tk+1)+A(tk). Tail 62->2, 63->0. lgkm(0) covers ds_reads.
// B swizzle seg^=(ro>>1)&3 on global source; VERIFIED conflict-free.
// Epilogue: 32x128 wave tile; bn<16 Q+rope*KAPPA; 16-19 K+rope; 20-23 V^T.
// ---------------------------------------------------------------------------
__global__ __launch_bounds__(256, 3) void gemm_qkv(const bf16* __restrict__ A,
                                                   const bf16* __restrict__ Bw,
                                                   const float* __restrict__ fc,
                                                   const float* __restrict__ fs,
                                                   bf16* __restrict__ Qro,
                                                   bf16* __restrict__ Kro,
                                                   bf16* __restrict__ Vt) {
  const int K = 2048;
  __shared__ bf16 Bs[3][128][32];  // 24 KB ring
  const int t = threadIdx.x;
  const int wave = t >> 6, lane = t & 63, qd = lane >> 4, ln = lane & 15;
  const int bn = blockIdx.x;  // 0..23 (Q:0-15, K:16-19, V:20-23)
  const size_t bm = (size_t)blockIdx.y * 128;

  // A: wave-private 32-row strip, direct from fragment-shuffled xb.
  const int mblk = (int)(blockIdx.y * 2) + (wave >> 1);
  const int j0 = (wave & 1) * 2;
  const char* Aw = (const char*)A + (size_t)mblk * 262144 +
                   (size_t)j0 * 1024 + (size_t)lane * 16;
  // B: row-major wqkv panel for this 128-col block.
  const bf16* Bb = Bw + (size_t)bn * 128 * K;

  auto stageB = [&](int tk, int slot) {
#pragma unroll
    for (int sub = 0; sub < 2; sub++) {
      int e = sub * 256 + t;
      int ro = e >> 2, gs = (e & 3) ^ ((ro >> 1) & 3);
      load_lds16(Bb + (size_t)ro * K + tk * 32 + gs * 8,
                 (char*)Bs + slot * 8192 + sub * 4096 + wave * 1024);
    }
  };

  f32x4 acc[2][8] = {};
  const int segoff = (qd ^ ((ln >> 1) & 3)) << 4;
  bf16x8 a0[2], a1[2];

  // Prologue: stage B(0),B(1); load A(0); land everything once.
  stageB(0, 0);
  stageB(1, 1);
#pragma unroll
  for (int i = 0; i < 2; i++)
    a0[i] = *(const bf16x8*)(Aw + (size_t)i * 1024);
  asm volatile("s_waitcnt vmcnt(0)" ::: "memory");
  __builtin_amdgcn_s_barrier();

  // Iter tk: stage B(tk+2), load A(tk+1)->na, ds_read B(tk), wait, 16 MFMA.
  auto step = [&](int tk, bf16x8 (&ca)[2], bf16x8 (&na)[2]) {
    if (tk < 62) stageB(tk + 2, (tk + 2) % 3);
    if (tk < 63) {
#pragma unroll
      for (int i = 0; i < 2; i++)
        na[i] = *(const bf16x8*)(Aw + (size_t)(tk + 1) * 4096 + i * 1024);
    }
    const char* Bsl = (const char*)Bs + (tk % 3) * 8192;
    bf16x8 bf[8];
#pragma unroll
    for (int j = 0; j < 8; j++)
      bf[j] = *(const bf16x8*)(Bsl + (j * 16 + ln) * 64 + segoff);
    if (tk <= 61) asm volatile("s_waitcnt lgkmcnt(0) vmcnt(4)" ::: "memory");
    else if (tk == 62) asm volatile("s_waitcnt lgkmcnt(0) vmcnt(2)" ::: "memory");
    else asm volatile("s_waitcnt lgkmcnt(0) vmcnt(0)" ::: "memory");
    __builtin_amdgcn_sched_barrier(0);
    __builtin_amdgcn_s_setprio(1);
#pragma unroll
    for (int i = 0; i < 2; i++)
#pragma unroll
      for (int j = 0; j < 8; j++)
        acc[i][j] = __builtin_amdgcn_mfma_f32_16x16x32_bf16(ca[i], bf[j],
                                                            acc[i][j], 0, 0, 0);
    __builtin_amdgcn_s_setprio(0);
    if (tk < 63) __builtin_amdgcn_s_barrier();
  };

  for (int tk = 0; tk < 64; tk += 2) {
    step(tk, a0, a1);
    step(tk + 1, a1, a0);
  }

  // ---- epilogue (round-0 math, 32x128 wave tile) ----
  const int b = (int)(bm >> 11);
  const int sb = (int)(bm & 2047) + wave * 32;
  const bool odd = ln & 1;

  if (bn < 20) {  // Q or K: rope, head-major output
    const bool isQ = bn < 16;
    const float kap = isQ ? KAPPA : 1.0f;
    const int hbase = isQ ? bn * 2 : (bn - 16) * 2;
#pragma unroll
    for (int j = 0; j < 8; j++) {
      const int hh = hbase + (j >> 2);
      bf16* dst = isQ ? (Qro + ((size_t)(b * 32 + hh) * 2048) * 64)
                      : (Kro + ((size_t)(b * 8 + hh) * 2048) * 64);
      const int d = (j & 3) * 16 + ln;
      const int i_f = d >> 1;
#pragma unroll
      for (int i = 0; i < 2; i++) {
#pragma unroll
        for (int r = 0; r < 4; r++) {
          int s = sb + i * 16 + qd * 4 + r;
          float v = acc[i][j][r];
          float p = __shfl_xor(v, 1);
          float cv = fc[s * 32 + i_f] * kap;
          float sv = fs[s * 32 + i_f] * kap;
          float o = odd ? (p * sv + v * cv) : (v * cv - p * sv);
          dst[(size_t)s * 64 + d] = (bf16)o;
        }
      }
    }
  } else {  // V: write transposed (B,8,64,S)
#pragma unroll
    for (int j = 0; j < 8; j++) {
      const int kh = (bn - 20) * 2 + (j >> 2);
      const int d = (j & 3) * 16 + ln;
#pragma unroll
      for (int i = 0; i < 2; i++) {
        int s = sb + i * 16 + qd * 4;
        bf16x4 ov = {(bf16)acc[i][j][0], (bf16)acc[i][j][1],
                     (bf16)acc[i][j][2], (bf16)acc[i][j][3]};
        *(bf16x4*)&Vt[((size_t)(b * 8 + kh) * 64 + d) * 2048 + s] = ov;
      }
    }
  }
}

// ---------------------------------------------------------------------------
// Output projection GEMM -- ZERO-DUPLICATION (r11's validated principle
// applied): old form loaded the shared 64-col B panel once PER WAVE PAIR
// (x2 duplication, 20KB L2/block/iter). Now B is WAVE-PRIVATE: each wave
// owns a 32-col strip (2 frags direct-to-reg from shuffled wob); A staged
// once through the 3-slot LDS ring shared by all waves. 12KB L2/block/iter.
// 64x128 tile, 4 waves (each 64 rows x 32 cols, acc[4][2], 8 MFMA/iter),
// grid (16,64) = 1024 = 4 blocks/CU, LDS 12KB.
// vmcnt ledger: per-iter issues [stage(tk+2):1, B(tk+1):2]; steady wait
//   lgkm(0) vmcnt(3) retires S(tk+1)+B(tk) (queue order S<B), leaving
//   S(tk+2)+B(tk+1)=3. Tail: tk==62 -> vmcnt(2) (retires S63+B62),
//   tk==63 -> vmcnt(0). Prologue [B0:2,S0:1,S1:1] -> vmcnt(1).
// ---------------------------------------------------------------------------
__global__ __launch_bounds__(256, 4) void gemm_bt(const bf16* __restrict__ A,
                                                  const bf16* __restrict__ Bw,
                                                  float* __restrict__ C) {
  const int K = 2048, N = 2048;
  __shared__ bf16 As[3][64][32];  // 12 KB ring
  const int t = threadIdx.x;
  const int wave = t >> 6, lane = t & 63, qd = lane >> 4, ln = lane & 15;
  const size_t bm = (size_t)blockIdx.y * 64;
  const size_t bn = (size_t)blockIdx.x * 128;

  const bf16* Ab = A + bm * (size_t)K;
  // B: wave-private 32-col strip from fragment-shuffled wob.
  const int nblk = (int)(bn >> 6) + (wave >> 1);
  const char* Bb = (const char*)Bw + (size_t)nblk * 262144 +
                   (size_t)((wave & 1) * 2) * 1024 + (size_t)lane * 16;

  auto stage = [&](int tk, int slot) {
    int ro = t >> 2, gs = (t & 3) ^ ((ro >> 1) & 3);
    load_lds16(Ab + (size_t)ro * K + tk * 32 + gs * 8,
               (char*)As + slot * 4096 + wave * 1024);
  };

  f32x4 acc[4][2] = {};
  const int segoff = (qd ^ ((ln >> 1) & 3)) << 4;
  bf16x8 b0[2], b1[2];

  // Prologue: B(0):2, stage(0):1, stage(1):1 -> need B0+S0 -> vmcnt(1).
#pragma unroll
  for (int j = 0; j < 2; j++)
    b0[j] = *(const bf16x8*)(Bb + (size_t)j * 1024);
  stage(0, 0);
  stage(1, 1);
  asm volatile("s_waitcnt vmcnt(1)" ::: "memory");
  __builtin_amdgcn_s_barrier();

  auto step = [&](int tk, bf16x8 (&cb)[2], bf16x8 (&nb)[2]) {
    if (tk < 62) stage(tk + 2, (tk + 2) % 3);
    if (tk < 63) {
#pragma unroll
      for (int j = 0; j < 2; j++)
        nb[j] = *(const bf16x8*)(Bb + (size_t)(tk + 1) * 4096 + j * 1024);
    }
    const char* Asl = (const char*)As + (tk % 3) * 4096;
    bf16x8 af[4];
#pragma unroll
    for (int i = 0; i < 4; i++)
      af[i] = *(const bf16x8*)(Asl + (i * 16 + ln) * 64 + segoff);
    if (tk <= 61) asm volatile("s_waitcnt lgkmcnt(0) vmcnt(3)" ::: "memory");
    else if (tk == 62) asm volatile("s_waitcnt lgkmcnt(0) vmcnt(2)" ::: "memory");
    else asm volatile("s_waitcnt lgkmcnt(0) vmcnt(0)" ::: "memory");
    __builtin_amdgcn_sched_barrier(0);
    __builtin_amdgcn_s_setprio(1);
#pragma unroll
    for (int i = 0; i < 4; i++)
#pragma unroll
      for (int j = 0; j < 2; j++)
        acc[i][j] = __builtin_amdgcn_mfma_f32_16x16x32_bf16(af[i], cb[j],
                                                            acc[i][j], 0, 0, 0);
    __builtin_amdgcn_s_setprio(0);
    if (tk < 63) __builtin_amdgcn_s_barrier();
  };

  for (int tk = 0; tk < 64; tk += 2) {
    step(tk, b0, b1);
    step(tk + 1, b1, b0);
  }

#pragma unroll
  for (int i = 0; i < 4; i++)
#pragma unroll
    for (int j = 0; j < 2; j++)
#pragma unroll
      for (int r = 0; r < 4; r++) {
        size_t row = bm + i * 16 + qd * 4 + r;
        size_t col = bn + wave * 32 + j * 16 + ln;
        C[row * N + col] = acc[i][j][r];
      }
}

// ---------------------------------------------------------------------------
// Flash attention (r5/r11 form, verified, unchanged). S^T formulation,
// causal, log2-domain fixed-point softmax p = 2^(s-16). Q fragments in
// registers; K/V 2-slot ring staged at top of iteration; one __syncthreads
// per tile. Q:(B,32,S,64) K:(B,8,S,64) Vt:(B,8,64,S) -> O:(B,S,32,64)
// ---------------------------------------------------------------------------
__global__ __launch_bounds__(256, 3) void attn_fwd(const bf16* __restrict__ Q,
                                                   const bf16* __restrict__ Kg,
                                                   const bf16* __restrict__ Vg,
                                                   bf16* __restrict__ O) {
  __shared__ bf16 Ks[2][64][64];  // 16 KB ring
  __shared__ bf16 Vs[2][64][64];  // 16 KB ring, [d][k]
  __shared__ bf16 Ps[128][64];    // [q][k], swizzled
  const int t = threadIdx.x;
  const int wave = t >> 6, lane = t & 63, qd = lane >> 4, ln = lane & 15;
  const int bid = blockIdx.x;
  const int qt = 15 - (bid >> 6);  // longest blocks dispatch first
  const int bh = bid & 63;
  const int b = bh >> 5, h = bh & 31, kh = h >> 2;
  const bf16* Qb = Q + ((size_t)(b * 32 + h) * 2048 + qt * 128) * 64;  // contiguous
  const bf16* Kb = Kg + (size_t)(b * 8 + kh) * 2048 * 64;              // contiguous
  const bf16* Vb = Vg + (size_t)(b * 8 + kh) * 64 * 2048;              // row stride 2048
  char* PsB = (char*)Ps;

  bf16x8 qf[2][2];
#pragma unroll
  for (int kk = 0; kk < 2; kk++)
#pragma unroll
    for (int mi = 0; mi < 2; mi++)
      qf[kk][mi] = *(const bf16x8*)(Qb + (wave * 32 + mi * 16 + ln) * 64 +
                                    (kk * 4 + qd) * 8);

  auto stageKV = [&](int kb, int buf) {
#pragma unroll
    for (int i = 0; i < 2; i++) {
      int e = i * 256 + t;
      int row = e >> 3, sg = (e & 7) ^ (row & 7);
      load_lds16(Kb + (size_t)(kb * 64 + row) * 64 + sg * 8,
                 (char*)Ks + buf * 8192 + i * 4096 + wave * 1024);
      load_lds16(Vb + (size_t)row * 2048 + kb * 64 + sg * 8,
                 (char*)Vs + buf * 8192 + i * 4096 + wave * 1024);
    }
  };

  f32x4 o_acc[4][2] = {};
  float l_st[2] = {0.f, 0.f};
  const int q0 = qt * 128 + wave * 32;
  const int nkb = 2 * qt + 2;

  stageKV(0, 0);
  __syncthreads();  // K0/V0 landed (vmcnt drain)

  for (int kb = 0; kb < nkb; kb++) {
    const int cur = kb & 1;
    if (kb + 1 < nkb) stageKV(kb + 1, cur ^ 1);
    const char* Ksl = (const char*)Ks + cur * 8192;
    const char* Vsl = (const char*)Vs + cur * 8192;

    // S^T = K*Q^T
    f32x4 s_acc[4][2] = {};
#pragma unroll
    for (int kk = 0; kk < 2; kk++) {
      bf16x8 ak[4];
#pragma unroll
      for (int j = 0; j < 4; j++) {
        int row = j * 16 + ln;
        int ph = (kk * 4 + qd) ^ (ln & 7);
        ak[j] = *(const bf16x8*)(Ksl + row * 128 + ph * 16);
      }
#pragma unroll
      for (int j = 0; j < 4; j++)
#pragma unroll
        for (int mi = 0; mi < 2; mi++)
          s_acc[j][mi] = __builtin_amdgcn_mfma_f32_16x16x32_bf16(
              ak[j], qf[kk][mi], s_acc[j][mi], 0, 0, 0);
    }

    // fixed-point softmax: p = 2^(s-16); masked -> exact 0
    auto smax = [&](auto maskc) {
      constexpr bool MASK = decltype(maskc)::value;
#pragma unroll
      for (int mi = 0; mi < 2; mi++) {
        const int qv = q0 + mi * 16 + ln;
        const int prow = wave * 32 + mi * 16 + ln;
        float rs = 0.f;
#pragma unroll
        for (int j = 0; j < 4; j++) {
          bf16x4 pk;
#pragma unroll
          for (int r = 0; r < 4; r++) {
            float s = s_acc[j][mi][r];
            if (MASK) {
              int k_glob = kb * 64 + j * 16 + qd * 4 + r;
              if (k_glob > qv) s = -1e5f;
            }
            float pv = exp2_fast(s - 16.f);
            rs += pv;
            pk[r] = (bf16)pv;
          }
          int ps = (j * 2 + (qd >> 1)) ^ (ln & 7);
          *(bf16x4*)(PsB + prow * 128 + ps * 16 + (qd & 1) * 8) = pk;
        }
        l_st[mi] += rs;
      }
    };
    if (kb * 64 + 63 > q0) smax(std::true_type{});
    else smax(std::false_type{});

    // O^T += V^T * P^T  (Ps wave-private; lgkmcnt orders write->read)
#pragma unroll
    for (int kk = 0; kk < 2; kk++) {
      bf16x8 av[4], bp[2];
#pragma unroll
      for (int dj = 0; dj < 4; dj++) {
        int row = dj * 16 + ln;
        int ph = (kk * 4 + qd) ^ (ln & 7);
        av[dj] = *(const bf16x8*)(Vsl + row * 128 + ph * 16);
      }
#pragma unroll
      for (int mi = 0; mi < 2; mi++) {
        int prow = wave * 32 + mi * 16 + ln;
        int ph = (kk * 4 + qd) ^ (ln & 7);
        bp[mi] = *(const bf16x8*)(PsB + prow * 128 + ph * 16);
      }
#pragma unroll
      for (int dj = 0; dj < 4; dj++)
#pragma unroll
        for (int mi = 0; mi < 2; mi++)
          o_acc[dj][mi] = __builtin_amdgcn_mfma_f32_16x16x32_bf16(
              av[dj], bp[mi], o_acc[dj][mi], 0, 0, 0);
    }

    __syncthreads();
  }

  // epilogue: reduce l across quads (each quad summed a disjoint k-subset)
#pragma unroll
  for (int mi = 0; mi < 2; mi++) {
    float lt = l_st[mi];
    lt += __shfl_xor(lt, 16);
    lt += __shfl_xor(lt, 32);
    float inv = 1.f / lt;
    int q_idx = qt * 128 + wave * 32 + mi * 16 + ln;
#pragma unroll
    for (int dj = 0; dj < 4; dj++) {
      bf16x4 ov;
#pragma unroll
      for (int r = 0; r < 4; r++) ov[r] = (bf16)(o_acc[dj][mi][r] * inv);
      *(bf16x4*)&O[((size_t)(b * 2048 + q_idx) * 32 + h) * 64 + dj * 16 + qd * 4] = ov;
    }
  }
}

// ---------------------------------------------------------------------------
extern "C" void kernel_launch(void* const* d_in, const int* in_sizes, int n_in,
                              void* d_out, int out_size, void* d_ws,
                              size_t ws_size, hipStream_t stream) {
  const float* x = (const float*)d_in[0];
  const float* fc = (const float*)d_in[1];
  const float* fs = (const float*)d_in[2];
  const float* wq = (const float*)d_in[3];
  const float* wk = (const float*)d_in[4];
  const float* wv = (const float*)d_in[5];
  const float* wo = (const float*)d_in[6];
  float* out = (float*)d_out;

  char* ws = (char*)d_ws;
  const size_t MB = (size_t)1 << 20;
  bf16* xb   = (bf16*)(ws + 0 * MB);   // 16 MB (4096,2048) fragment-shuffled
  bf16* wqkv = (bf16*)(ws + 16 * MB);  // 12 MB row-major concat
  bf16* wob  = (bf16*)(ws + 28 * MB);  // 8 MB fragment-shuffled
  bf16* Qro  = (bf16*)(ws + 36 * MB);  // 16 MB (B,32,S,64), roped*KAPPA
  bf16* Kro  = (bf16*)(ws + 52 * MB);  // 4 MB  (B,8,S,64), roped
  bf16* Vt   = (bf16*)(ws + 56 * MB);  // 4 MB  (B,8,64,S)
  bf16* Oa   = (bf16*)(ws + 60 * MB);  // 16 MB (B,S,32,64)

  dim3 blk(256);
  f2b_all<<<12288, blk, 0, stream>>>(x, wq, wk, wv, wo, xb, wqkv, wob);
  gemm_qkv<<<dim3(24, 32), blk, 0, stream>>>(xb, wqkv, fc, fs, Qro, Kro, Vt);
  attn_fwd<<<1024, blk, 0, stream>>>(Qro, Kro, Vt, Oa);
  gemm_bt<<<dim3(16, 64), blk, 0, stream>>>(Oa, wob, out);
}